// Round 5
// baseline (73.101 us; speedup 1.0000x reference)
//
#include <hip/hip_runtime.h>

#define NPTS 4096
#define BATCH 8
#define SENT 1e5f

typedef __attribute__((ext_vector_type(8))) short short8;   // 8 bf16 = 4 VGPR (MFMA A/B frag)
typedef __attribute__((ext_vector_type(4))) float f32x4;    // MFMA C/D frag

__device__ __forceinline__ unsigned short f2bf(float f) {
    unsigned u = __float_as_uint(f);
    unsigned r = (u + 0x7FFFu + ((u >> 16) & 1u)) >> 16;    // RNE
    return (unsigned short)r;
}
__device__ __forceinline__ float bf2f(unsigned short s) {
    return __uint_as_float(((unsigned)s) << 16);
}
__device__ __forceinline__ void split3(float v, unsigned short* h, unsigned short* m, unsigned short* l) {
    unsigned short hh = f2bf(v); float r1 = v - bf2f(hh);
    unsigned short mm = f2bf(r1); float r2 = r1 - bf2f(mm);
    *h = hh; *m = mm; *l = f2bf(r2);
}
__device__ __forceinline__ unsigned pk2(unsigned short a, unsigned short b) {
    return (unsigned)a | ((unsigned)b << 16);
}

// Prep: per point build the K=32 MFMA rows for A (clean, scaled -2, 3-way split,
// + x2 split + ones) and B (predp, 3-way split, + ones + y2 split), stored in
// lane-major tile layout so the main kernel's loads are lane-linear coalesced.
// K pairing: k0-8: th*(bh,bm,bl); k9-14: tm*(bh,bm); k15-17: tl*bh;
//            k18-20: x2(h,m,l)*1; k21-23: 1*y2(h,m,l); k24-31: 0.
// => D[n,m] = x2_n + y2_m - 2*clean_n.predp_m  (err ~2^-24)
__global__ __launch_bounds__(256) void prep_kernel(
    const float* __restrict__ pred, const float* __restrict__ target,
    const int* __restrict__ mask, const float* __restrict__ points,
    uint4* __restrict__ Abuf, uint4* __restrict__ Bbuf, float* __restrict__ out)
{
    int idx = blockIdx.x * 256 + threadIdx.x;      // 0..32767
    if (idx == 0) out[0] = 0.0f;                   // re-zeroed every call (atomicAdd target)
    int b = idx >> 12, n = idx & (NPTS - 1);
    int g = idx;
    int mk = mask[g];
    float px = points[g*3+0], py = points[g*3+1], pz = points[g*3+2];
    float cx = px + target[g*3+0], cy = py + target[g*3+1], cz = pz + target[g*3+2];
    float ex = px + pred[g*3+0],  ey = py + pred[g*3+1],  ez = pz + pred[g*3+2];
    if (!mk) { cx = cy = cz = SENT; ex = ey = ez = SENT; }  // sentinel masking

    unsigned short one = 0x3F80;  // bf16(1.0)

    unsigned short thx,tmx,tlx, thy,tmy,tly, thz,tmz,tlz, x2h,x2m,x2l;
    split3(-2.0f*cx, &thx,&tmx,&tlx);
    split3(-2.0f*cy, &thy,&tmy,&tly);
    split3(-2.0f*cz, &thz,&tmz,&tlz);
    split3(cx*cx + cy*cy + cz*cz, &x2h,&x2m,&x2l);
    unsigned short ak[24] = {thx,thy,thz, thx,thy,thz, thx,thy,thz,
                             tmx,tmy,tmz, tmx,tmy,tmz, tlx,tly,tlz,
                             x2h,x2m,x2l, one,one,one};

    unsigned short bhx,bmx,blx, bhy,bmy,bly, bhz,bmz,blz, y2h,y2m,y2l;
    split3(ex, &bhx,&bmx,&blx);
    split3(ey, &bhy,&bmy,&bly);
    split3(ez, &bhz,&bmz,&blz);
    split3(ex*ex + ey*ey + ez*ez, &y2h,&y2m,&y2l);
    unsigned short bk[24] = {bhx,bhy,bhz, bmx,bmy,bmz, blx,bly,blz,
                             bhx,bhy,bhz, bmx,bmy,bmz, bhx,bhy,bhz,
                             one,one,one, y2h,y2m,y2l};

    int tile = (b << 8) + (n >> 4);
    int r = n & 15;
#pragma unroll
    for (int gg = 0; gg < 3; gg++) {
        uint4 ca = make_uint4(pk2(ak[gg*8+0],ak[gg*8+1]), pk2(ak[gg*8+2],ak[gg*8+3]),
                              pk2(ak[gg*8+4],ak[gg*8+5]), pk2(ak[gg*8+6],ak[gg*8+7]));
        uint4 cb = make_uint4(pk2(bk[gg*8+0],bk[gg*8+1]), pk2(bk[gg*8+2],bk[gg*8+3]),
                              pk2(bk[gg*8+4],bk[gg*8+5]), pk2(bk[gg*8+6],bk[gg*8+7]));
        Abuf[tile*64 + gg*16 + r] = ca;
        Bbuf[tile*64 + gg*16 + r] = cb;
    }
    uint4 z = make_uint4(0,0,0,0);
    Abuf[tile*64 + 48 + r] = z;
    Bbuf[tile*64 + 48 + r] = z;
}

// Main: one wave per 128x128 macro-tile of D per batch. 64 MFMAs, register-
// resident running row/col mins, shfl-xor finalize, partials to global.
__global__ __launch_bounds__(256) void tiles_kernel(
    const short8* __restrict__ Abuf, const short8* __restrict__ Bbuf,
    float* __restrict__ rowpart, float* __restrict__ colpart)
{
    int bid = blockIdx.x;
    int b = bid >> 8;
    int rem = bid & 255;
    int nmacro = rem >> 3;
    int mblock = rem & 7;
    int wave = threadIdx.x >> 6;
    int lane = threadIdx.x & 63;
    int mmacro = (mblock << 2) + wave;

    short8 Af[8], Bf[8];
#pragma unroll
    for (int i = 0; i < 8; i++)
        Af[i] = Abuf[((b << 8) + (nmacro << 3) + i) * 64 + lane];
#pragma unroll
    for (int i = 0; i < 8; i++)
        Bf[i] = Bbuf[((b << 8) + (mmacro << 3) + i) * 64 + lane];

    f32x4 rm[8];
    float cm[8];
#pragma unroll
    for (int i = 0; i < 8; i++) { rm[i] = (f32x4){3e38f,3e38f,3e38f,3e38f}; cm[i] = 3e38f; }
    f32x4 zero = (f32x4){0.f,0.f,0.f,0.f};

#pragma unroll
    for (int mt = 0; mt < 8; mt++) {
#pragma unroll
        for (int nt = 0; nt < 8; nt++) {
            f32x4 d = __builtin_amdgcn_mfma_f32_16x16x32_bf16(Af[nt], Bf[mt], zero, 0, 0, 0);
            rm[nt] = __builtin_elementwise_min(rm[nt], d);
            cm[mt] = fminf(cm[mt], fminf(fminf(d[0], d[1]), fminf(d[2], d[3])));
        }
    }

    // rowmin: C/D row = (lane>>4)*4+reg, col = lane&15 -> reduce across lane&15
#pragma unroll
    for (int nt = 0; nt < 8; nt++) {
#pragma unroll
        for (int s = 1; s <= 8; s <<= 1) {
            f32x4 o;
            o[0] = __shfl_xor(rm[nt][0], s, 64);
            o[1] = __shfl_xor(rm[nt][1], s, 64);
            o[2] = __shfl_xor(rm[nt][2], s, 64);
            o[3] = __shfl_xor(rm[nt][3], s, 64);
            rm[nt] = __builtin_elementwise_min(rm[nt], o);
        }
    }
    if ((lane & 15) == 0) {
        int rowbase = ((b << 5) + mmacro) * NPTS + (nmacro << 7) + ((lane >> 4) << 2);
#pragma unroll
        for (int nt = 0; nt < 8; nt++) {
            float4 st = make_float4(rm[nt][0], rm[nt][1], rm[nt][2], rm[nt][3]);
            *(float4*)&rowpart[rowbase + (nt << 4)] = st;
        }
    }
    // colmin: reduce across the 4 lane-groups
#pragma unroll
    for (int mt = 0; mt < 8; mt++) {
        cm[mt] = fminf(cm[mt], __shfl_xor(cm[mt], 16, 64));
        cm[mt] = fminf(cm[mt], __shfl_xor(cm[mt], 32, 64));
    }
    if (lane < 16) {
        int colbase = ((b << 5) + nmacro) * NPTS + (mmacro << 7) + lane;
#pragma unroll
        for (int mt = 0; mt < 8; mt++)
            colpart[colbase + (mt << 4)] = cm[mt];
    }
}

// Reduce: 8 segs x 8 batches. Min 32 partials per dir, clamp, row-mask,
// block-reduce, one atomicAdd of (S_seg/C_b)/BATCH.
__global__ __launch_bounds__(256) void reduce_kernel(
    const int* __restrict__ mask, const float* __restrict__ rowpart,
    const float* __restrict__ colpart, float* __restrict__ out)
{
    __shared__ float s_sum[4], s_cnt[4];
    int b = blockIdx.x >> 3, seg = blockIdx.x & 7;
    int t = threadIdx.x;

    float cnt = 0.f;
    for (int i = t; i < NPTS; i += 256) cnt += (float)mask[b * NPTS + i];

    float sum = 0.f;
#pragma unroll
    for (int s = 0; s < 2; s++) {
        int n = (seg << 9) + (s << 8) + t;
        if (mask[b * NPTS + n]) {
            float mx = 3e38f, my = 3e38f;
#pragma unroll
            for (int j = 0; j < 32; j++) {
                mx = fminf(mx, rowpart[((b << 5) + j) * NPTS + n]);
                my = fminf(my, colpart[((b << 5) + j) * NPTS + n]);
            }
            sum += fmaxf(mx, 0.f) + fmaxf(my, 0.f);
        }
    }
    for (int off = 32; off; off >>= 1) {
        sum += __shfl_down(sum, off, 64);
        cnt += __shfl_down(cnt, off, 64);
    }
    if ((t & 63) == 0) { s_sum[t >> 6] = sum; s_cnt[t >> 6] = cnt; }
    __syncthreads();
    if (t == 0) {
        float S = 0.f, C = 0.f;
#pragma unroll
        for (int w = 0; w < 4; w++) { S += s_sum[w]; C += s_cnt[w]; }
        atomicAdd(out, (S / C) * 0.125f);
    }
}

extern "C" void kernel_launch(void* const* d_in, const int* in_sizes, int n_in,
                              void* d_out, int out_size, void* d_ws, size_t ws_size,
                              hipStream_t stream) {
    const float* pred   = (const float*)d_in[0];
    const float* target = (const float*)d_in[1];
    const int*   mask   = (const int*)d_in[2];
    const float* points = (const float*)d_in[3];
    float* out = (float*)d_out;

    uint4* Abuf    = (uint4*)d_ws;                                  // 2 MB
    uint4* Bbuf    = (uint4*)((char*)d_ws + (2u << 20));            // 2 MB
    float* rowpart = (float*)((char*)d_ws + (4u << 20));            // 4 MB
    float* colpart = (float*)((char*)d_ws + (8u << 20));            // 4 MB

    prep_kernel<<<BATCH * NPTS / 256, 256, 0, stream>>>(pred, target, mask, points, Abuf, Bbuf, out);
    tiles_kernel<<<2048, 256, 0, stream>>>((const short8*)Abuf, (const short8*)Bbuf, rowpart, colpart);
    reduce_kernel<<<64, 256, 0, stream>>>(mask, rowpart, colpart, out);
}

// Round 6
// 37.254 us; speedup vs baseline: 1.9622x; 1.9622x over previous
//
#include <hip/hip_runtime.h>

#define NPTS 4096
#define BATCH 8
#define BIGF 1e10f

typedef __attribute__((ext_vector_type(8))) short short8;   // 8 bf16 (MFMA A/B frag)
typedef __attribute__((ext_vector_type(4))) float f32x4;    // MFMA C/D frag
typedef unsigned short us;

__device__ __forceinline__ us f2bf(float f) {
    unsigned u = __float_as_uint(f);
    unsigned r = (u + 0x7FFFu + ((u >> 16) & 1u)) >> 16;    // RNE
    return (us)r;
}
__device__ __forceinline__ float bf2f(us s) { return __uint_as_float(((unsigned)s) << 16); }
__device__ __forceinline__ void split3(float v, us* h, us* m, us* l) {
    us hh = f2bf(v); float r1 = v - bf2f(hh);
    us mm = f2bf(r1); float r2 = r1 - bf2f(mm);
    *h = hh; *m = mm; *l = f2bf(r2);
}
__device__ __forceinline__ unsigned pk2(us a, us b) { return (unsigned)a | ((unsigned)b << 16); }

// K=32 packing (verified absmax 0.0 in R5):
//   dot(ak,bk) = x2 + w - 2*x.y  (3-way bf16 splits, err ~1e-5)
// A-side: t = -2*coords splits + x2 splits + ones
// B-side: coords splits + ones + w splits  (w = y2 + mask_penalty)
__device__ __forceinline__ void store_frags(
    float x, float y, float z, float x2v, float wv,
    uint4* __restrict__ Adst, uint4* __restrict__ Bdst, int r)
{
    const us one = 0x3F80;  // bf16(1.0)
    us thx,tmx,tlx, thy,tmy,tly, thz,tmz,tlz, x2h,x2m,x2l;
    split3(-2.f*x,&thx,&tmx,&tlx);
    split3(-2.f*y,&thy,&tmy,&tly);
    split3(-2.f*z,&thz,&tmz,&tlz);
    split3(x2v,&x2h,&x2m,&x2l);
    us ak[24] = {thx,thy,thz, thx,thy,thz, thx,thy,thz,
                 tmx,tmy,tmz, tmx,tmy,tmz, tlx,tly,tlz,
                 x2h,x2m,x2l, one,one,one};
    us bhx,bmx,blx, bhy,bmy,bly, bhz,bmz,blz, wh,wm,wl;
    split3(x,&bhx,&bmx,&blx);
    split3(y,&bhy,&bmy,&bly);
    split3(z,&bhz,&bmz,&blz);
    split3(wv,&wh,&wm,&wl);
    us bk[24] = {bhx,bhy,bhz, bmx,bmy,bmz, blx,bly,blz,
                 bhx,bhy,bhz, bmx,bmy,bmz, bhx,bhy,bhz,
                 one,one,one, wh,wm,wl};
#pragma unroll
    for (int gg = 0; gg < 3; gg++) {
        Adst[gg*16+r] = make_uint4(pk2(ak[gg*8+0],ak[gg*8+1]), pk2(ak[gg*8+2],ak[gg*8+3]),
                                   pk2(ak[gg*8+4],ak[gg*8+5]), pk2(ak[gg*8+6],ak[gg*8+7]));
        Bdst[gg*16+r] = make_uint4(pk2(bk[gg*8+0],bk[gg*8+1]), pk2(bk[gg*8+2],bk[gg*8+3]),
                                   pk2(bk[gg*8+4],bk[gg*8+5]), pk2(bk[gg*8+6],bk[gg*8+7]));
    }
    uint4 zz = make_uint4(0,0,0,0);
    Adst[48+r] = zz;
    Bdst[48+r] = zz;
}

// Prep: one thread per point; build A/B frags for both dirs.
// Abuf[0]=clean-as-rows, Abuf[1]=predp-as-rows; Bbuf[0]=predp-as-cols, Bbuf[1]=clean-as-cols.
__global__ __launch_bounds__(256) void prep_kernel(
    const float* __restrict__ pred, const float* __restrict__ target,
    const int* __restrict__ mask, const float* __restrict__ points,
    uint4* __restrict__ Abuf, uint4* __restrict__ Bbuf, float* __restrict__ out)
{
    int idx = blockIdx.x * 256 + threadIdx.x;     // 0..32767
    if (idx == 0) out[0] = 0.f;                   // zeroed before main's atomicAdds
    int b = idx >> 12, n = idx & (NPTS - 1);
    float px = points[idx*3+0], py = points[idx*3+1], pz = points[idx*3+2];
    float cx = px + target[idx*3+0], cy = py + target[idx*3+1], cz = pz + target[idx*3+2];
    float ex = px + pred[idx*3+0],  ey = py + pred[idx*3+1],  ez = pz + pred[idx*3+2];
    float c2 = cx*cx + cy*cy + cz*cz;
    float e2 = ex*ex + ey*ey + ez*ez;
    float pen = mask[idx] ? 0.f : BIGF;
    int tile = n >> 4, r = n & 15;
    uint4* A0 = Abuf + ((size_t)(0*BATCH+b)*256 + tile)*64;
    uint4* A1 = Abuf + ((size_t)(1*BATCH+b)*256 + tile)*64;
    uint4* B0 = Bbuf + ((size_t)(0*BATCH+b)*256 + tile)*64;
    uint4* B1 = Bbuf + ((size_t)(1*BATCH+b)*256 + tile)*64;
    store_frags(cx,cy,cz, c2, c2+pen, A0, B1, r);   // clean: rows of dir0, cols of dir1
    store_frags(ex,ey,ez, e2, e2+pen, A1, B0, r);   // predp: rows of dir1, cols of dir0
}

// Main: block = (dir, b, 128-row strip); 4 waves x 32 rows; stream all 4096 cols
// through double-buffered LDS chunks (256 cols = 16KB) via global_load_lds.
// Row-mins complete in-block -> masked sum -> one atomicAdd. No reduce kernel.
__global__ __launch_bounds__(256, 4) void main_kernel(
    const int* __restrict__ mask,
    const uint4* __restrict__ Abuf, const uint4* __restrict__ Bbuf,
    float* __restrict__ out)
{
    __shared__ uint4 Bsh[2][1024];    // 2 x 16KB
    __shared__ float scnt[4], swave[4];

    int bid = blockIdx.x;
    int strip = bid & 31, b = (bid >> 5) & 7, dir = bid >> 8;
    int t = threadIdx.x, w = t >> 6, lane = t & 63;

    const uint4*  Bsrc = Bbuf + ((size_t)(dir * BATCH + b) * 256) * 64;
    const short8* Asrc = (const short8*)(Abuf + ((size_t)(dir * BATCH + b) * 256) * 64);

    // stage chunk 0
    {
        const char* src = (const char*)Bsrc;
        char* dst = (char*)&Bsh[0][0];
#pragma unroll
        for (int r = 0; r < 4; r++) {
            int off = (r * 256 + t) * 16;
            __builtin_amdgcn_global_load_lds(
                (const __attribute__((address_space(1))) void*)(src + off),
                (__attribute__((address_space(3))) void*)(dst + off), 16, 0, 0);
        }
    }

    // A fragments: wave w owns row-tiles strip*8 + w*2 {+0,+1}
    short8 Af0 = Asrc[(strip * 8 + w * 2 + 0) * 64 + lane];
    short8 Af1 = Asrc[(strip * 8 + w * 2 + 1) * 64 + lane];

    // per-batch valid count (overlaps with stage-0 latency)
    int csum = 0;
    const int4* m4 = (const int4*)(mask + b * NPTS);
#pragma unroll
    for (int r = 0; r < 4; r++) { int4 v = m4[r * 256 + t]; csum += v.x + v.y + v.z + v.w; }
#pragma unroll
    for (int s = 32; s; s >>= 1) csum += __shfl_down(csum, s, 64);
    if (lane == 0) scnt[w] = (float)csum;

    f32x4 rm0 = {3e38f,3e38f,3e38f,3e38f}, rm1 = rm0;
    f32x4 zero = {0.f,0.f,0.f,0.f};

    __syncthreads();   // chunk 0 resident; scnt visible

    for (int c = 0; c < 16; c++) {
        int nb = c & 1;
        if (c < 15) {   // prefetch next chunk into other buffer
            const char* src = (const char*)(Bsrc + (size_t)(c + 1) * 16 * 64);
            char* dst = (char*)&Bsh[nb ^ 1][0];
#pragma unroll
            for (int r = 0; r < 4; r++) {
                int off = (r * 256 + t) * 16;
                __builtin_amdgcn_global_load_lds(
                    (const __attribute__((address_space(1))) void*)(src + off),
                    (__attribute__((address_space(3))) void*)(dst + off), 16, 0, 0);
            }
        }
        const short8* Bt = (const short8*)&Bsh[nb][0];
#pragma unroll
        for (int p = 0; p < 8; p++) {
            short8 b0 = Bt[(2 * p + 0) * 64 + lane];
            short8 b1 = Bt[(2 * p + 1) * 64 + lane];
            f32x4 d00 = __builtin_amdgcn_mfma_f32_16x16x32_bf16(Af0, b0, zero, 0, 0, 0);
            f32x4 d01 = __builtin_amdgcn_mfma_f32_16x16x32_bf16(Af0, b1, zero, 0, 0, 0);
            f32x4 d10 = __builtin_amdgcn_mfma_f32_16x16x32_bf16(Af1, b0, zero, 0, 0, 0);
            f32x4 d11 = __builtin_amdgcn_mfma_f32_16x16x32_bf16(Af1, b1, zero, 0, 0, 0);
#pragma unroll
            for (int j = 0; j < 4; j++) {
                rm0[j] = fminf(fminf(rm0[j], d00[j]), d01[j]);   // -> v_min3_f32
                rm1[j] = fminf(fminf(rm1[j], d10[j]), d11[j]);
            }
        }
        __syncthreads();   // ds_reads done + staged loads drained
    }

    // reduce row-mins across the 16 columns held by lanes (col = lane&15)
#pragma unroll
    for (int s = 1; s <= 8; s <<= 1) {
        f32x4 o0, o1;
#pragma unroll
        for (int j = 0; j < 4; j++) { o0[j] = __shfl_xor(rm0[j], s, 64); o1[j] = __shfl_xor(rm1[j], s, 64); }
#pragma unroll
        for (int j = 0; j < 4; j++) { rm0[j] = fminf(rm0[j], o0[j]); rm1[j] = fminf(rm1[j], o1[j]); }
    }
    // C/D row = (lane>>4)*4 + j (m89-verified); lanes 0,16,32,48 hold rows g*4+j
    float part = 0.f;
    if ((lane & 15) == 0) {
        int g = lane >> 4;
        int rowbase = b * NPTS + strip * 128 + w * 32 + g * 4;
#pragma unroll
        for (int j = 0; j < 4; j++) {
            if (mask[rowbase + j])      part += fmaxf(rm0[j], 0.f);
            if (mask[rowbase + 16 + j]) part += fmaxf(rm1[j], 0.f);
        }
    }
    part += __shfl_xor(part, 16, 64);
    part += __shfl_xor(part, 32, 64);
    if (lane == 0) swave[w] = part;
    __syncthreads();
    if (t == 0) {
        float C = scnt[0] + scnt[1] + scnt[2] + scnt[3];
        float S = swave[0] + swave[1] + swave[2] + swave[3];
        atomicAdd(out, S / C * 0.125f);
    }
}

extern "C" void kernel_launch(void* const* d_in, const int* in_sizes, int n_in,
                              void* d_out, int out_size, void* d_ws, size_t ws_size,
                              hipStream_t stream) {
    const float* pred   = (const float*)d_in[0];
    const float* target = (const float*)d_in[1];
    const int*   mask   = (const int*)d_in[2];
    const float* points = (const float*)d_in[3];
    float* out = (float*)d_out;

    uint4* Abuf = (uint4*)d_ws;                          // 4 MB
    uint4* Bbuf = (uint4*)((char*)d_ws + (4u << 20));    // 4 MB

    prep_kernel<<<BATCH * NPTS / 256, 256, 0, stream>>>(pred, target, mask, points, Abuf, Bbuf, out);
    main_kernel<<<512, 256, 0, stream>>>(mask, Abuf, Bbuf, out);
}

// Round 7
// 36.155 us; speedup vs baseline: 2.0219x; 1.0304x over previous
//
#include <hip/hip_runtime.h>

#define NPTS 4096
#define BATCH 8
#define BIGF 1e10f

typedef __attribute__((ext_vector_type(8))) short short8;   // 8 bf16 (MFMA A/B frag)
typedef __attribute__((ext_vector_type(4))) float f32x4;    // MFMA C/D frag
typedef unsigned short us;

__device__ __forceinline__ us f2bf(float f) {
    unsigned u = __float_as_uint(f);
    unsigned r = (u + 0x7FFFu + ((u >> 16) & 1u)) >> 16;    // RNE
    return (us)r;
}
__device__ __forceinline__ float bf2f(us s) { return __uint_as_float(((unsigned)s) << 16); }
__device__ __forceinline__ void split3(float v, us* h, us* m, us* l) {
    us hh = f2bf(v); float r1 = v - bf2f(hh);
    us mm = f2bf(r1); float r2 = r1 - bf2f(mm);
    *h = hh; *m = mm; *l = f2bf(r2);
}
__device__ __forceinline__ unsigned pk2(us a, us b) { return (unsigned)a | ((unsigned)b << 16); }

// K=32 packing (verified absmax 0.0 in R5/R6):
//   dot(ak,bk) = x2 + w - 2*x.y  (3-way bf16 splits, err ~1e-5)
__device__ __forceinline__ void store_frags(
    float x, float y, float z, float x2v, float wv,
    uint4* __restrict__ Adst, uint4* __restrict__ Bdst, int r)
{
    const us one = 0x3F80;  // bf16(1.0)
    us thx,tmx,tlx, thy,tmy,tly, thz,tmz,tlz, x2h,x2m,x2l;
    split3(-2.f*x,&thx,&tmx,&tlx);
    split3(-2.f*y,&thy,&tmy,&tly);
    split3(-2.f*z,&thz,&tmz,&tlz);
    split3(x2v,&x2h,&x2m,&x2l);
    us ak[24] = {thx,thy,thz, thx,thy,thz, thx,thy,thz,
                 tmx,tmy,tmz, tmx,tmy,tmz, tlx,tly,tlz,
                 x2h,x2m,x2l, one,one,one};
    us bhx,bmx,blx, bhy,bmy,bly, bhz,bmz,blz, wh,wm,wl;
    split3(x,&bhx,&bmx,&blx);
    split3(y,&bhy,&bmy,&bly);
    split3(z,&bhz,&bmz,&blz);
    split3(wv,&wh,&wm,&wl);
    us bk[24] = {bhx,bhy,bhz, bmx,bmy,bmz, blx,bly,blz,
                 bhx,bhy,bhz, bmx,bmy,bmz, bhx,bhy,bhz,
                 one,one,one, wh,wm,wl};
#pragma unroll
    for (int gg = 0; gg < 3; gg++) {
        Adst[gg*16+r] = make_uint4(pk2(ak[gg*8+0],ak[gg*8+1]), pk2(ak[gg*8+2],ak[gg*8+3]),
                                   pk2(ak[gg*8+4],ak[gg*8+5]), pk2(ak[gg*8+6],ak[gg*8+7]));
        Bdst[gg*16+r] = make_uint4(pk2(bk[gg*8+0],bk[gg*8+1]), pk2(bk[gg*8+2],bk[gg*8+3]),
                                   pk2(bk[gg*8+4],bk[gg*8+5]), pk2(bk[gg*8+6],bk[gg*8+7]));
    }
    uint4 zz = make_uint4(0,0,0,0);
    Adst[48+r] = zz;
    Bdst[48+r] = zz;
}

// Prep: one thread per point; build A/B frags for both dirs.
__global__ __launch_bounds__(256) void prep_kernel(
    const float* __restrict__ pred, const float* __restrict__ target,
    const int* __restrict__ mask, const float* __restrict__ points,
    uint4* __restrict__ Abuf, uint4* __restrict__ Bbuf, float* __restrict__ out)
{
    int idx = blockIdx.x * 256 + threadIdx.x;     // 0..32767
    if (idx == 0) out[0] = 0.f;                   // zeroed before main's atomicAdds
    int b = idx >> 12, n = idx & (NPTS - 1);
    float px = points[idx*3+0], py = points[idx*3+1], pz = points[idx*3+2];
    float cx = px + target[idx*3+0], cy = py + target[idx*3+1], cz = pz + target[idx*3+2];
    float ex = px + pred[idx*3+0],  ey = py + pred[idx*3+1],  ez = pz + pred[idx*3+2];
    float c2 = cx*cx + cy*cy + cz*cz;
    float e2 = ex*ex + ey*ey + ez*ez;
    float pen = mask[idx] ? 0.f : BIGF;
    int tile = n >> 4, r = n & 15;
    uint4* A0 = Abuf + ((size_t)(0*BATCH+b)*256 + tile)*64;
    uint4* A1 = Abuf + ((size_t)(1*BATCH+b)*256 + tile)*64;
    uint4* B0 = Bbuf + ((size_t)(0*BATCH+b)*256 + tile)*64;
    uint4* B1 = Bbuf + ((size_t)(1*BATCH+b)*256 + tile)*64;
    store_frags(cx,cy,cz, c2, c2+pen, A0, B1, r);   // clean: rows of dir0, cols of dir1
    store_frags(ex,ey,ez, e2, e2+pen, A1, B0, r);   // predp: rows of dir1, cols of dir0
}

// Main: block = (dir, b, 128-row strip). XCD-SWIZZLED mapping: (dir,b) in the
// LOW 4 bits of blockIdx so all 32 strips sharing one 256KB B-slice land on the
// SAME XCD (bid%8 round-robin) -> per-XCD L2 working set ~1MB (was ~4.5MB,
// thrashing). 4 waves x 32 rows; stream 4096 cols through double-buffered LDS
// via global_load_lds; row-mins in-block -> masked sum -> one atomicAdd.
__global__ __launch_bounds__(256, 4) void main_kernel(
    const int* __restrict__ mask,
    const uint4* __restrict__ Abuf, const uint4* __restrict__ Bbuf,
    float* __restrict__ out)
{
    __shared__ uint4 Bsh[2][1024];    // 2 x 16KB
    __shared__ float scnt[4], swave[4];

    int bid = blockIdx.x;
    int db = bid & 15;                 // (dir*8+b) in LOW bits -> pinned XCD
    int strip = bid >> 4;              // 0..31
    int b = db & 7, dir = db >> 3;
    int t = threadIdx.x, w = t >> 6, lane = t & 63;

    const uint4*  Bsrc = Bbuf + ((size_t)(dir * BATCH + b) * 256) * 64;
    const short8* Asrc = (const short8*)(Abuf + ((size_t)(dir * BATCH + b) * 256) * 64);

    // stage chunk 0
    {
        const char* src = (const char*)Bsrc;
        char* dst = (char*)&Bsh[0][0];
#pragma unroll
        for (int r = 0; r < 4; r++) {
            int off = (r * 256 + t) * 16;
            __builtin_amdgcn_global_load_lds(
                (const __attribute__((address_space(1))) void*)(src + off),
                (__attribute__((address_space(3))) void*)(dst + off), 16, 0, 0);
        }
    }

    // A fragments: wave w owns row-tiles strip*8 + w*2 {+0,+1}
    short8 Af0 = Asrc[(strip * 8 + w * 2 + 0) * 64 + lane];
    short8 Af1 = Asrc[(strip * 8 + w * 2 + 1) * 64 + lane];

    // per-batch valid count (overlaps with stage-0 latency)
    int csum = 0;
    const int4* m4 = (const int4*)(mask + b * NPTS);
#pragma unroll
    for (int r = 0; r < 4; r++) { int4 v = m4[r * 256 + t]; csum += v.x + v.y + v.z + v.w; }
#pragma unroll
    for (int s = 32; s; s >>= 1) csum += __shfl_down(csum, s, 64);
    if (lane == 0) scnt[w] = (float)csum;

    f32x4 rm0 = {3e38f,3e38f,3e38f,3e38f}, rm1 = rm0;
    f32x4 zero = {0.f,0.f,0.f,0.f};

    __syncthreads();   // chunk 0 resident; scnt visible

    for (int c = 0; c < 16; c++) {
        int nb = c & 1;
        if (c < 15) {   // prefetch next chunk into other buffer
            const char* src = (const char*)(Bsrc + (size_t)(c + 1) * 16 * 64);
            char* dst = (char*)&Bsh[nb ^ 1][0];
#pragma unroll
            for (int r = 0; r < 4; r++) {
                int off = (r * 256 + t) * 16;
                __builtin_amdgcn_global_load_lds(
                    (const __attribute__((address_space(1))) void*)(src + off),
                    (__attribute__((address_space(3))) void*)(dst + off), 16, 0, 0);
            }
        }
        const short8* Bt = (const short8*)&Bsh[nb][0];
#pragma unroll
        for (int p = 0; p < 8; p++) {
            short8 b0 = Bt[(2 * p + 0) * 64 + lane];
            short8 b1 = Bt[(2 * p + 1) * 64 + lane];
            f32x4 d00 = __builtin_amdgcn_mfma_f32_16x16x32_bf16(Af0, b0, zero, 0, 0, 0);
            f32x4 d01 = __builtin_amdgcn_mfma_f32_16x16x32_bf16(Af0, b1, zero, 0, 0, 0);
            f32x4 d10 = __builtin_amdgcn_mfma_f32_16x16x32_bf16(Af1, b0, zero, 0, 0, 0);
            f32x4 d11 = __builtin_amdgcn_mfma_f32_16x16x32_bf16(Af1, b1, zero, 0, 0, 0);
#pragma unroll
            for (int j = 0; j < 4; j++) {
                rm0[j] = fminf(fminf(rm0[j], d00[j]), d01[j]);   // -> v_min3_f32
                rm1[j] = fminf(fminf(rm1[j], d10[j]), d11[j]);
            }
        }
        __syncthreads();   // ds_reads done + staged loads drained
    }

    // reduce row-mins across the 16 columns held by lanes (col = lane&15)
#pragma unroll
    for (int s = 1; s <= 8; s <<= 1) {
        f32x4 o0, o1;
#pragma unroll
        for (int j = 0; j < 4; j++) { o0[j] = __shfl_xor(rm0[j], s, 64); o1[j] = __shfl_xor(rm1[j], s, 64); }
#pragma unroll
        for (int j = 0; j < 4; j++) { rm0[j] = fminf(rm0[j], o0[j]); rm1[j] = fminf(rm1[j], o1[j]); }
    }
    // C/D row = (lane>>4)*4 + j (m89-verified); lanes 0,16,32,48 hold rows g*4+j
    float part = 0.f;
    if ((lane & 15) == 0) {
        int g = lane >> 4;
        int rowbase = b * NPTS + strip * 128 + w * 32 + g * 4;
#pragma unroll
        for (int j = 0; j < 4; j++) {
            if (mask[rowbase + j])      part += fmaxf(rm0[j], 0.f);
            if (mask[rowbase + 16 + j]) part += fmaxf(rm1[j], 0.f);
        }
    }
    part += __shfl_xor(part, 16, 64);
    part += __shfl_xor(part, 32, 64);
    if (lane == 0) swave[w] = part;
    __syncthreads();
    if (t == 0) {
        float C = scnt[0] + scnt[1] + scnt[2] + scnt[3];
        float S = swave[0] + swave[1] + swave[2] + swave[3];
        atomicAdd(out, S / C * 0.125f);
    }
}

extern "C" void kernel_launch(void* const* d_in, const int* in_sizes, int n_in,
                              void* d_out, int out_size, void* d_ws, size_t ws_size,
                              hipStream_t stream) {
    const float* pred   = (const float*)d_in[0];
    const float* target = (const float*)d_in[1];
    const int*   mask   = (const int*)d_in[2];
    const float* points = (const float*)d_in[3];
    float* out = (float*)d_out;

    uint4* Abuf = (uint4*)d_ws;                          // 4 MB
    uint4* Bbuf = (uint4*)((char*)d_ws + (4u << 20));    // 4 MB

    prep_kernel<<<BATCH * NPTS / 256, 256, 0, stream>>>(pred, target, mask, points, Abuf, Bbuf, out);
    main_kernel<<<512, 256, 0, stream>>>(mask, Abuf, Bbuf, out);
}

// Round 8
// 34.065 us; speedup vs baseline: 2.1459x; 1.0614x over previous
//
#include <hip/hip_runtime.h>

#define NPTS 4096
#define BATCH 8
#define BIGF 1e10f

typedef __attribute__((ext_vector_type(8))) short short8;   // 8 bf16 (MFMA A/B frag)
typedef __attribute__((ext_vector_type(4))) float f32x4;    // MFMA C/D frag
typedef unsigned short us;

// truncating bf16 split: remainders are EXACT (same-exponent subtract), total
// err ~2^-24 |v| -- cheaper than RNE (no rounding adds)
__device__ __forceinline__ us trbf(float f) { return (us)(__float_as_uint(f) >> 16); }
__device__ __forceinline__ float bff(us s)  { return __uint_as_float(((unsigned)s) << 16); }
__device__ __forceinline__ void split3(float v, us* h, us* m, us* l) {
    *h = trbf(v); float r1 = v - bff(*h);
    *m = trbf(r1); float r2 = r1 - bff(*m);
    *l = trbf(r2);
}
__device__ __forceinline__ unsigned pk2(us a, us b) { return (unsigned)a | ((unsigned)b << 16); }

// K=32 pairing (HW-verified absmax 0.0 in R5-R7):
//   dot(ak,bk) = x2 + w - 2*x.y
// ak: {th*3 x3, tm*3 x2, tl*3, x2 splits, ones}   (t = -2*coord splits)
// bk: {bh*3, bm*3, bl*3, bh*3, bm*3, bh*3, ones, w splits}
__device__ __forceinline__ void apack(float x, float y, float z,
                                      uint4* __restrict__ dst, int r) {
    const us one = 0x3F80;
    us thx,tmx,tlx, thy,tmy,tly, thz,tmz,tlz, x2h,x2m,x2l;
    split3(-2.f*x,&thx,&tmx,&tlx);
    split3(-2.f*y,&thy,&tmy,&tly);
    split3(-2.f*z,&thz,&tmz,&tlz);
    split3(x*x + y*y + z*z,&x2h,&x2m,&x2l);
    us ak[24] = {thx,thy,thz, thx,thy,thz, thx,thy,thz,
                 tmx,tmy,tmz, tmx,tmy,tmz, tlx,tly,tlz,
                 x2h,x2m,x2l, one,one,one};
#pragma unroll
    for (int gg = 0; gg < 3; gg++)
        dst[gg*16+r] = make_uint4(pk2(ak[gg*8+0],ak[gg*8+1]), pk2(ak[gg*8+2],ak[gg*8+3]),
                                  pk2(ak[gg*8+4],ak[gg*8+5]), pk2(ak[gg*8+6],ak[gg*8+7]));
    dst[48+r] = make_uint4(0,0,0,0);
}

__device__ __forceinline__ void bpack(
    const float* __restrict__ points, const float* __restrict__ bres,
    const int* __restrict__ mask, int g, uint4* __restrict__ dst, int r)
{
    float x = points[g*3+0] + bres[g*3+0];
    float y = points[g*3+1] + bres[g*3+1];
    float z = points[g*3+2] + bres[g*3+2];
    float wq = x*x + y*y + z*z + (mask[g] ? 0.f : BIGF);   // col-side mask penalty
    const us one = 0x3F80;
    us bhx,bmx,blx, bhy,bmy,bly, bhz,bmz,blz, wh,wm,wl;
    split3(x,&bhx,&bmx,&blx);
    split3(y,&bhy,&bmy,&bly);
    split3(z,&bhz,&bmz,&blz);
    split3(wq,&wh,&wm,&wl);
    us bk[24] = {bhx,bhy,bhz, bmx,bmy,bmz, blx,bly,blz,
                 bhx,bhy,bhz, bmx,bmy,bmz, bhx,bhy,bhz,
                 one,one,one, wh,wm,wl};
#pragma unroll
    for (int gg = 0; gg < 3; gg++)
        dst[gg*16+r] = make_uint4(pk2(bk[gg*8+0],bk[gg*8+1]), pk2(bk[gg*8+2],bk[gg*8+3]),
                                  pk2(bk[gg*8+4],bk[gg*8+5]), pk2(bk[gg*8+6],bk[gg*8+7]));
    dst[48+r] = make_uint4(0,0,0,0);
}

// Single fused kernel. Block = (dir, b, 128-row strip); 4 waves x 32 rows.
// B-fragments for each 256-col chunk are COMPUTED into double-buffered LDS
// (no prep kernel, no global frag traffic); A-fragments computed once into LDS.
// Row-mins complete in-block -> masked sum -> one atomicAdd (out zeroed by a
// hipMemsetAsync before launch).
__global__ __launch_bounds__(256, 2) void fused_kernel(
    const float* __restrict__ pred, const float* __restrict__ target,
    const int* __restrict__ mask, const float* __restrict__ points,
    float* __restrict__ out)
{
    __shared__ uint4 Bsh[2][1024];    // 2 x 16KB (256 cols per chunk)
    __shared__ uint4 Ash[512];        // 8KB: 128 rows
    __shared__ float scnt[4], swave[4];

    int bid = blockIdx.x;
    int strip = bid & 31, b = (bid >> 5) & 7, dir = bid >> 8;
    int t = threadIdx.x, w = t >> 6, lane = t & 63;

    const float* __restrict__ ares = dir ? pred : target;   // rows: dir0=clean, dir1=predp
    const float* __restrict__ bres = dir ? target : pred;   // cols: dir0=predp, dir1=clean

    // A-prep: this block's 128 row points
    if (t < 128) {
        int g = b * NPTS + strip * 128 + t;
        float x = points[g*3+0] + ares[g*3+0];
        float y = points[g*3+1] + ares[g*3+1];
        float z = points[g*3+2] + ares[g*3+2];
        apack(x, y, z, Ash + (t >> 4) * 64, t & 15);
    }
    // B-prep chunk 0
    bpack(points, bres, mask, b * NPTS + t, &Bsh[0][(t >> 4) * 64], t & 15);

    // per-batch valid count
    int csum = 0;
    const int4* m4 = (const int4*)(mask + b * NPTS);
#pragma unroll
    for (int r = 0; r < 4; r++) { int4 v = m4[r * 256 + t]; csum += v.x + v.y + v.z + v.w; }
#pragma unroll
    for (int s = 32; s; s >>= 1) csum += __shfl_down(csum, s, 64);
    if (lane == 0) scnt[w] = (float)csum;

    f32x4 rm0 = {3e38f,3e38f,3e38f,3e38f}, rm1 = rm0;
    f32x4 zero = {0.f,0.f,0.f,0.f};

    __syncthreads();

    short8 Af0 = ((const short8*)Ash)[(w * 2 + 0) * 64 + lane];
    short8 Af1 = ((const short8*)Ash)[(w * 2 + 1) * 64 + lane];

    for (int c = 0; c < 16; c++) {
        int nb = c & 1;
        if (c < 15)   // compute next chunk's B-frags into the other buffer
            bpack(points, bres, mask, b * NPTS + (c + 1) * 256 + t,
                  &Bsh[nb ^ 1][(t >> 4) * 64], t & 15);
        const short8* Bt = (const short8*)&Bsh[nb][0];
#pragma unroll
        for (int p = 0; p < 8; p++) {
            short8 b0 = Bt[(2 * p + 0) * 64 + lane];
            short8 b1 = Bt[(2 * p + 1) * 64 + lane];
            f32x4 d00 = __builtin_amdgcn_mfma_f32_16x16x32_bf16(Af0, b0, zero, 0, 0, 0);
            f32x4 d01 = __builtin_amdgcn_mfma_f32_16x16x32_bf16(Af0, b1, zero, 0, 0, 0);
            f32x4 d10 = __builtin_amdgcn_mfma_f32_16x16x32_bf16(Af1, b0, zero, 0, 0, 0);
            f32x4 d11 = __builtin_amdgcn_mfma_f32_16x16x32_bf16(Af1, b1, zero, 0, 0, 0);
#pragma unroll
            for (int j = 0; j < 4; j++) {
                rm0[j] = fminf(fminf(rm0[j], d00[j]), d01[j]);   // -> v_min3_f32
                rm1[j] = fminf(fminf(rm1[j], d10[j]), d11[j]);
            }
        }
        __syncthreads();
    }

    // reduce row-mins across the 16 columns held per lane group (col = lane&15)
#pragma unroll
    for (int s = 1; s <= 8; s <<= 1) {
        f32x4 o0, o1;
#pragma unroll
        for (int j = 0; j < 4; j++) { o0[j] = __shfl_xor(rm0[j], s, 64); o1[j] = __shfl_xor(rm1[j], s, 64); }
#pragma unroll
        for (int j = 0; j < 4; j++) { rm0[j] = fminf(rm0[j], o0[j]); rm1[j] = fminf(rm1[j], o1[j]); }
    }
    // C/D row = (lane>>4)*4 + j; lanes 0,16,32,48 hold rows g*4+j
    float part = 0.f;
    if ((lane & 15) == 0) {
        int g = lane >> 4;
        int rowbase = b * NPTS + strip * 128 + w * 32 + g * 4;
#pragma unroll
        for (int j = 0; j < 4; j++) {
            if (mask[rowbase + j])      part += fmaxf(rm0[j], 0.f);
            if (mask[rowbase + 16 + j]) part += fmaxf(rm1[j], 0.f);
        }
    }
    part += __shfl_xor(part, 16, 64);
    part += __shfl_xor(part, 32, 64);
    if (lane == 0) swave[w] = part;
    __syncthreads();
    if (t == 0) {
        float C = scnt[0] + scnt[1] + scnt[2] + scnt[3];
        float S = swave[0] + swave[1] + swave[2] + swave[3];
        atomicAdd(out, S / C * 0.125f);
    }
}

extern "C" void kernel_launch(void* const* d_in, const int* in_sizes, int n_in,
                              void* d_out, int out_size, void* d_ws, size_t ws_size,
                              hipStream_t stream) {
    const float* pred   = (const float*)d_in[0];
    const float* target = (const float*)d_in[1];
    const int*   mask   = (const int*)d_in[2];
    const float* points = (const float*)d_in[3];
    float* out = (float*)d_out;

    hipMemsetAsync(out, 0, sizeof(float), stream);   // capturable memset node
    fused_kernel<<<512, 256, 0, stream>>>(pred, target, mask, points, out);
}

// Round 9
// 31.798 us; speedup vs baseline: 2.2990x; 1.0713x over previous
//
#include <hip/hip_runtime.h>

#define NPTS 4096
#define BATCH 8
#define BIGF 1e10f

typedef __attribute__((ext_vector_type(8))) short short8;   // 8 bf16 (MFMA A/B frag)
typedef __attribute__((ext_vector_type(4))) float f32x4;    // MFMA C/D frag
typedef unsigned short us;

// truncating bf16 split: remainders are EXACT (same-exponent subtract), total
// err ~2^-24 |v|
__device__ __forceinline__ us trbf(float f) { return (us)(__float_as_uint(f) >> 16); }
__device__ __forceinline__ float bff(us s)  { return __uint_as_float(((unsigned)s) << 16); }
__device__ __forceinline__ void split3(float v, us* h, us* m, us* l) {
    *h = trbf(v); float r1 = v - bff(*h);
    *m = trbf(r1); float r2 = r1 - bff(*m);
    *l = trbf(r2);
}
__device__ __forceinline__ unsigned pk2(us a, us b) { return (unsigned)a | ((unsigned)b << 16); }

// K=32 pairing (HW-verified absmax 0.0 in R5-R8):
//   dot(ak,bk) = x2 + w - 2*x.y
__device__ __forceinline__ void apack(float x, float y, float z,
                                      uint4* __restrict__ dst, int r) {
    const us one = 0x3F80;
    us thx,tmx,tlx, thy,tmy,tly, thz,tmz,tlz, x2h,x2m,x2l;
    split3(-2.f*x,&thx,&tmx,&tlx);
    split3(-2.f*y,&thy,&tmy,&tly);
    split3(-2.f*z,&thz,&tmz,&tlz);
    split3(x*x + y*y + z*z,&x2h,&x2m,&x2l);
    us ak[24] = {thx,thy,thz, thx,thy,thz, thx,thy,thz,
                 tmx,tmy,tmz, tmx,tmy,tmz, tlx,tly,tlz,
                 x2h,x2m,x2l, one,one,one};
#pragma unroll
    for (int gg = 0; gg < 3; gg++)
        dst[gg*16+r] = make_uint4(pk2(ak[gg*8+0],ak[gg*8+1]), pk2(ak[gg*8+2],ak[gg*8+3]),
                                  pk2(ak[gg*8+4],ak[gg*8+5]), pk2(ak[gg*8+6],ak[gg*8+7]));
    dst[48+r] = make_uint4(0,0,0,0);
}

__device__ __forceinline__ void bpack(
    const float* __restrict__ points, const float* __restrict__ bres,
    const int* __restrict__ mask, int g, uint4* __restrict__ dst, int r)
{
    float x = points[g*3+0] + bres[g*3+0];
    float y = points[g*3+1] + bres[g*3+1];
    float z = points[g*3+2] + bres[g*3+2];
    float wq = x*x + y*y + z*z + (mask[g] ? 0.f : BIGF);   // col-side mask penalty
    const us one = 0x3F80;
    us bhx,bmx,blx, bhy,bmy,bly, bhz,bmz,blz, wh,wm,wl;
    split3(x,&bhx,&bmx,&blx);
    split3(y,&bhy,&bmy,&bly);
    split3(z,&bhz,&bmz,&blz);
    split3(wq,&wh,&wm,&wl);
    us bk[24] = {bhx,bhy,bhz, bmx,bmy,bmz, blx,bly,blz,
                 bhx,bhy,bhz, bmx,bmy,bmz, bhx,bhy,bhz,
                 one,one,one, wh,wm,wl};
#pragma unroll
    for (int gg = 0; gg < 3; gg++)
        dst[gg*16+r] = make_uint4(pk2(bk[gg*8+0],bk[gg*8+1]), pk2(bk[gg*8+2],bk[gg*8+3]),
                                  pk2(bk[gg*8+4],bk[gg*8+5]), pk2(bk[gg*8+6],bk[gg*8+7]));
    dst[48+r] = make_uint4(0,0,0,0);
}

// Single fused kernel. Block = (dir, b, 128-row strip); 8 waves x 16 rows
// (512 threads) -> 16 waves/CU = 4 waves/SIMD (was 2). Streams 4096 cols in
// 8 chunks of 512 through double-buffered LDS; B-frags computed in-block.
// Row-mins in-block -> masked sum -> one atomicAdd (out zeroed by memset node).
__global__ __launch_bounds__(512, 4) void fused_kernel(
    const float* __restrict__ pred, const float* __restrict__ target,
    const int* __restrict__ mask, const float* __restrict__ points,
    float* __restrict__ out)
{
    __shared__ uint4 Bsh[2][2048];    // 2 x 32KB (512 cols per chunk)
    __shared__ uint4 Ash[512];        // 8KB: 128 rows
    __shared__ float scnt[8], swave[8];

    int bid = blockIdx.x;
    int strip = bid & 31, b = (bid >> 5) & 7, dir = bid >> 8;
    int t = threadIdx.x, w = t >> 6, lane = t & 63;

    const float* __restrict__ ares = dir ? pred : target;   // rows: dir0=clean, dir1=predp
    const float* __restrict__ bres = dir ? target : pred;   // cols: dir0=predp, dir1=clean

    // A-prep: this block's 128 row points
    if (t < 128) {
        int g = b * NPTS + strip * 128 + t;
        float x = points[g*3+0] + ares[g*3+0];
        float y = points[g*3+1] + ares[g*3+1];
        float z = points[g*3+2] + ares[g*3+2];
        apack(x, y, z, Ash + (t >> 4) * 64, t & 15);
    }
    // B-prep chunk 0: 512 threads, one col point each
    bpack(points, bres, mask, b * NPTS + t, &Bsh[0][(t >> 4) * 64], t & 15);

    // per-batch valid count (512 threads x 2 int4 = 4096 ints)
    int csum = 0;
    const int4* m4 = (const int4*)(mask + b * NPTS);
#pragma unroll
    for (int r = 0; r < 2; r++) { int4 v = m4[r * 512 + t]; csum += v.x + v.y + v.z + v.w; }
#pragma unroll
    for (int s = 32; s; s >>= 1) csum += __shfl_down(csum, s, 64);
    if (lane == 0) scnt[w] = (float)csum;

    f32x4 rm = {3e38f,3e38f,3e38f,3e38f};
    f32x4 zero = {0.f,0.f,0.f,0.f};

    __syncthreads();

    short8 Af = ((const short8*)Ash)[w * 64 + lane];   // wave w owns row-tile w

    for (int c = 0; c < 8; c++) {
        int nb = c & 1;
        if (c < 7)   // compute next chunk's B-frags into the other buffer
            bpack(points, bres, mask, b * NPTS + (c + 1) * 512 + t,
                  &Bsh[nb ^ 1][(t >> 4) * 64], t & 15);
        const short8* Bt = (const short8*)&Bsh[nb][0];
#pragma unroll
        for (int p = 0; p < 16; p++) {
            short8 b0 = Bt[(2 * p + 0) * 64 + lane];
            short8 b1 = Bt[(2 * p + 1) * 64 + lane];
            f32x4 d0 = __builtin_amdgcn_mfma_f32_16x16x32_bf16(Af, b0, zero, 0, 0, 0);
            f32x4 d1 = __builtin_amdgcn_mfma_f32_16x16x32_bf16(Af, b1, zero, 0, 0, 0);
#pragma unroll
            for (int j = 0; j < 4; j++)
                rm[j] = fminf(fminf(rm[j], d0[j]), d1[j]);   // -> v_min3_f32
        }
        __syncthreads();
    }

    // reduce row-mins across the 16 columns held per lane group (col = lane&15)
#pragma unroll
    for (int s = 1; s <= 8; s <<= 1) {
        f32x4 o;
#pragma unroll
        for (int j = 0; j < 4; j++) o[j] = __shfl_xor(rm[j], s, 64);
#pragma unroll
        for (int j = 0; j < 4; j++) rm[j] = fminf(rm[j], o[j]);
    }
    // C/D row = (lane>>4)*4 + j; lanes 0,16,32,48 hold rows g*4+j of tile w
    float part = 0.f;
    if ((lane & 15) == 0) {
        int g = lane >> 4;
        int rowbase = b * NPTS + strip * 128 + w * 16 + g * 4;
#pragma unroll
        for (int j = 0; j < 4; j++)
            if (mask[rowbase + j]) part += fmaxf(rm[j], 0.f);
    }
    part += __shfl_xor(part, 16, 64);
    part += __shfl_xor(part, 32, 64);
    if (lane == 0) swave[w] = part;
    __syncthreads();
    if (t == 0) {
        float C = 0.f, S = 0.f;
#pragma unroll
        for (int i = 0; i < 8; i++) { C += scnt[i]; S += swave[i]; }
        atomicAdd(out, S / C * 0.125f);
    }
}

extern "C" void kernel_launch(void* const* d_in, const int* in_sizes, int n_in,
                              void* d_out, int out_size, void* d_ws, size_t ws_size,
                              hipStream_t stream) {
    const float* pred   = (const float*)d_in[0];
    const float* target = (const float*)d_in[1];
    const int*   mask   = (const int*)d_in[2];
    const float* points = (const float*)d_in[3];
    float* out = (float*)d_out;

    hipMemsetAsync(out, 0, sizeof(float), stream);   // capturable memset node
    fused_kernel<<<512, 512, 0, stream>>>(pred, target, mask, points, out);
}

// Round 10
// 26.417 us; speedup vs baseline: 2.7672x; 1.2037x over previous
//
#include <hip/hip_runtime.h>

#define NPTS 4096
#define BATCH 8
#define BIGF 1e10f

typedef __attribute__((ext_vector_type(8))) short short8;    // 8 bf16 = 4 VGPR (32x32x16 A/B frag)
typedef __attribute__((ext_vector_type(16))) float f32x16;   // 32x32 C/D frag
typedef unsigned short us;

__device__ __forceinline__ us f2bf(float f) {                // RNE bf16 (unbiased)
    unsigned u = __float_as_uint(f);
    return (us)((u + 0x7FFFu + ((u >> 16) & 1u)) >> 16);
}
__device__ __forceinline__ float bff(us s) { return __uint_as_float(((unsigned)s) << 16); }
__device__ __forceinline__ void split2(float v, us* h, us* m) {
    *h = f2bf(v); *m = f2bf(v - bff(*h));                    // 2-way split, err ~2^-17 |v|
}
__device__ __forceinline__ unsigned pk2(us a, us b) { return (unsigned)a | ((unsigned)b << 16); }

// K=16 pairing (13 live slots):
//  ak: [thx,thy,thz, thx,thy,thz, tmx,tmy | tmz, x2h,x2m, 1,1, 0,0,0]
//  bk: [bhx,bhy,bhz, bmx,bmy,bmz, bhx,bhy | bhz, 1,1, wh,wm, 0,0,0]
//  dot = sum_c (th*bh + th*bm + tm*bh) + x2 + w  ~=  x2 + w - 2 x.y
// (t = -2*coord splits; dropped tm*bm ~ 2^-17|2xy|)
__device__ __forceinline__ void apackA(float x, float y, float z,
                                       uint4* __restrict__ dst, int row) {
    const us one = 0x3F80;
    us thx,tmx, thy,tmy, thz,tmz, x2h,x2m;
    split2(-2.f*x, &thx,&tmx);
    split2(-2.f*y, &thy,&tmy);
    split2(-2.f*z, &thz,&tmz);
    split2(x*x + y*y + z*z, &x2h,&x2m);
    dst[row]      = make_uint4(pk2(thx,thy), pk2(thz,thx), pk2(thy,thz), pk2(tmx,tmy));
    dst[row + 32] = make_uint4(pk2(tmz,x2h), pk2(x2m,one), pk2(one,0),   pk2(0,0));
}

__device__ __forceinline__ void bpackB(
    const float* __restrict__ points, const float* __restrict__ bres,
    const int* __restrict__ mask, int g, uint4* __restrict__ dst, int col)
{
    float x = points[g*3+0] + bres[g*3+0];
    float y = points[g*3+1] + bres[g*3+1];
    float z = points[g*3+2] + bres[g*3+2];
    float wq = x*x + y*y + z*z + (mask[g] ? 0.f : BIGF);     // col-side mask penalty
    const us one = 0x3F80;
    us bhx,bmx, bhy,bmy, bhz,bmz, wh,wm;
    split2(x, &bhx,&bmx);
    split2(y, &bhy,&bmy);
    split2(z, &bhz,&bmz);
    split2(wq, &wh,&wm);
    dst[col]      = make_uint4(pk2(bhx,bhy), pk2(bhz,bmx), pk2(bmy,bmz), pk2(bhx,bhy));
    dst[col + 32] = make_uint4(pk2(bhz,one), pk2(one,wh),  pk2(wm,0),    pk2(0,0));
}

// Single fused kernel, 32x32x16 MFMA. Block = (dir, b, 256-row strip);
// 8 waves x 32 rows. Streams 4096 cols in 8 chunks of 512 (16 col-tiles)
// through double-buffered LDS; B-frags computed in-block. One B-frag read
// feeds 1024 outputs (4x the 16x16 amortization). Row-mins in-block ->
// masked sum -> one atomicAdd (out zeroed by memset node).
__global__ __launch_bounds__(512, 2) void fused_kernel(
    const float* __restrict__ pred, const float* __restrict__ target,
    const int* __restrict__ mask, const float* __restrict__ points,
    float* __restrict__ out)
{
    __shared__ uint4 Bsh[2][16][64];   // 2 x 16KB: 16 col-tiles
    __shared__ uint4 Ash[8][64];       // 8KB: 8 row-tiles (256 rows)
    __shared__ float scnt[8], swave[8];

    int bid = blockIdx.x;              // 256 = 2 dir x 8 b x 16 strips
    int strip = bid & 15, b = (bid >> 4) & 7, dir = bid >> 7;
    int t = threadIdx.x, w = t >> 6, lane = t & 63;

    const float* __restrict__ ares = dir ? pred : target;    // rows: dir0=clean, dir1=predp
    const float* __restrict__ bres = dir ? target : pred;    // cols: dir0=predp, dir1=clean

    // A-prep: this block's 256 row points (threads 0..255)
    if (t < 256) {
        int g = b * NPTS + strip * 256 + t;
        float x = points[g*3+0] + ares[g*3+0];
        float y = points[g*3+1] + ares[g*3+1];
        float z = points[g*3+2] + ares[g*3+2];
        apackA(x, y, z, &Ash[t >> 5][0], t & 31);
    }
    // B-prep chunk 0: 512 threads, one col point each
    bpackB(points, bres, mask, b * NPTS + t, &Bsh[0][t >> 5][0], t & 31);

    // per-batch valid count
    int csum = 0;
    const int4* m4 = (const int4*)(mask + b * NPTS);
#pragma unroll
    for (int r = 0; r < 2; r++) { int4 v = m4[r * 512 + t]; csum += v.x + v.y + v.z + v.w; }
#pragma unroll
    for (int s = 32; s; s >>= 1) csum += __shfl_down(csum, s, 64);
    if (lane == 0) scnt[w] = (float)csum;

    float rm[16];
#pragma unroll
    for (int r = 0; r < 16; r++) rm[r] = 3e38f;
    f32x16 zero = {0.f,0.f,0.f,0.f,0.f,0.f,0.f,0.f,0.f,0.f,0.f,0.f,0.f,0.f,0.f,0.f};

    __syncthreads();

    short8 Af = ((const short8*)Ash)[w * 64 + lane];   // wave w = row-tile w (32 rows)

    for (int c = 0; c < 8; c++) {
        int nb = c & 1;
        if (c < 7)   // compute next chunk's B-frags into the other buffer
            bpackB(points, bres, mask, b * NPTS + (c + 1) * 512 + t,
                   &Bsh[nb ^ 1][t >> 5][0], t & 31);
        const short8* Bt = (const short8*)&Bsh[nb][0][0];
#pragma unroll
        for (int p = 0; p < 16; p += 2) {
            short8 b0 = Bt[(p + 0) * 64 + lane];
            short8 b1 = Bt[(p + 1) * 64 + lane];
            f32x16 d0 = __builtin_amdgcn_mfma_f32_32x32x16_bf16(Af, b0, zero, 0, 0, 0);
            f32x16 d1 = __builtin_amdgcn_mfma_f32_32x32x16_bf16(Af, b1, zero, 0, 0, 0);
#pragma unroll
            for (int r = 0; r < 16; r++)
                rm[r] = fminf(fminf(rm[r], d0[r]), d1[r]);   // -> v_min3_f32
        }
        __syncthreads();
    }

    // row-min finalize: col = lane&31 -> reduce across the 32-lane half
#pragma unroll
    for (int r = 0; r < 16; r++) {
#pragma unroll
        for (int s = 1; s <= 16; s <<= 1)
            rm[r] = fminf(rm[r], __shfl_xor(rm[r], s, 64));
    }
    // C/D row = (reg&3) + 8*(reg>>2) + 4*(lane>>5)  [m74/m101-verified]
    float part = 0.f;
    if ((lane & 31) == 0) {
        int h = lane >> 5;
        int rowbase = b * NPTS + strip * 256 + w * 32 + 4 * h;
#pragma unroll
        for (int r = 0; r < 16; r++) {
            int row = rowbase + (r & 3) + 8 * (r >> 2);
            if (mask[row]) part += fmaxf(rm[r], 0.f);
        }
    }
    part += __shfl_xor(part, 32, 64);
    if (lane == 0) swave[w] = part;
    __syncthreads();
    if (t == 0) {
        float C = 0.f, S = 0.f;
#pragma unroll
        for (int i = 0; i < 8; i++) { C += scnt[i]; S += swave[i]; }
        atomicAdd(out, S / C * 0.125f);
    }
}

extern "C" void kernel_launch(void* const* d_in, const int* in_sizes, int n_in,
                              void* d_out, int out_size, void* d_ws, size_t ws_size,
                              hipStream_t stream) {
    const float* pred   = (const float*)d_in[0];
    const float* target = (const float*)d_in[1];
    const int*   mask   = (const int*)d_in[2];
    const float* points = (const float*)d_in[3];
    float* out = (float*)d_out;

    hipMemsetAsync(out, 0, sizeof(float), stream);   // capturable memset node
    fused_kernel<<<256, 512, 0, stream>>>(pred, target, mask, points, out);
}